// Round 13
// baseline (413.728 us; speedup 1.0000x reference)
//
#include <hip/hip_runtime.h>
#include <stdint.h>

#define B_   4
#define S_   2048
#define D_   512
#define H_   8
#define DH_  64
#define V_   100000
#define P_   256
#define N_   (B_*S_)    // 8192 rows
#define NP_  (B_*P_)    // 1024 rows

typedef _Float16 f16;
typedef _Float16 f16x8 __attribute__((ext_vector_type(8)));
typedef float    f32x4 __attribute__((ext_vector_type(4)));
typedef uint32_t u32x4 __attribute__((ext_vector_type(4)));

#define MFMA16(a,b,c) __builtin_amdgcn_mfma_f32_16x16x32_f16((a),(b),(c),0,0,0)
#define GLDS16(gp, lp) __builtin_amdgcn_global_load_lds( \
    (const __attribute__((address_space(1))) void*)(gp), \
    (__attribute__((address_space(3))) void*)(lp), 16, 0, 0)

// counted-vmcnt + raw barrier
template<int N>
__device__ __forceinline__ void wait_barrier() {
  if constexpr (N == 0)
    asm volatile("s_waitcnt vmcnt(0)\ns_barrier" ::: "memory");
  else if constexpr (N == 3)
    asm volatile("s_waitcnt vmcnt(3)\ns_barrier" ::: "memory");
  else
    asm volatile("s_waitcnt vmcnt(4)\ns_barrier" ::: "memory");
}

// ---------------------------------------------------------------------------
// Weight-conversion job table
// ---------------------------------------------------------------------------
struct WJobs {
  const float* src[10];
  f16* dst[10];
  int K[10], N[10], tiles[10];
};

// ---------------------------------------------------------------------------
// prep kernel: wconv (10240 blocks) + bias concat (10) + embed (4096, 2 rows)
// ---------------------------------------------------------------------------
__global__ __launch_bounds__(256) void prep_kernel(WJobs jobs,
    const float* __restrict__ sbq, const float* __restrict__ sbk,
    const float* __restrict__ sbv, const float* __restrict__ cbk,
    const float* __restrict__ cbv, float* __restrict__ bqkv,
    float* __restrict__ bckv,
    const int* __restrict__ bytes_seq, const float* __restrict__ byte_emb,
    const float* __restrict__ ngram_emb, f16* __restrict__ out16)
{
  int bid = blockIdx.x;
  if (bid < 10240) {
    const int j = bid >> 10, tile = bid & 1023;
    if (tile >= jobs.tiles[j]) return;
    const int K = jobs.K[j], N = jobs.N[j];
    const int ntiles = N >> 5;
    const int kt = (tile / ntiles) << 5, nt = (tile % ntiles) << 5;
    __shared__ float T[32][33];
    const int t = threadIdx.x;
    const float* src = jobs.src[j];
    #pragma unroll
    for (int p = 0; p < 4; p++) {
      int lin = t + p * 256;
      int rr = lin >> 5, cc = lin & 31;
      T[rr][cc] = src[(size_t)(kt + rr) * N + nt + cc];
    }
    __syncthreads();
    f16* dst = jobs.dst[j];
    #pragma unroll
    for (int p = 0; p < 4; p++) {
      int lin = t + p * 256;
      int rr = lin >> 5, cc = lin & 31;
      dst[(size_t)(nt + rr) * K + kt + cc] = (f16)T[cc][rr];
    }
    return;
  }
  bid -= 10240;
  if (bid < 10) {
    int t = bid * 256 + threadIdx.x;
    if (t < 512)       bqkv[t] = sbq[t];
    else if (t < 1024) bqkv[t] = sbk[t - 512];
    else if (t < 1536) bqkv[t] = sbv[t - 1024];
    else if (t < 2048) bckv[t - 1536] = cbk[t - 1536];
    else if (t < 2560) bckv[t - 1536] = cbv[t - 2048];
    return;
  }
  bid -= 10;
  const int pos = bid * 2 + (threadIdx.x >> 7);
  const int b = pos / S_, s = pos % S_;
  const int* bs = bytes_seq + (size_t)b * S_;

  int w[8];
  #pragma unroll
  for (int k = 0; k < 8; k++) {
    int p = s - 7 + k;
    w[k] = (p >= 0) ? bs[p] : 0;
  }
  int idx[6];
  #pragma unroll
  for (int j = 0; j < 6; j++) {
    const int n = j + 3;
    int id = 0;
    if (s >= n - 1) {
      uint64_t h = 0;
      for (int k = 0; k < n; k++)
        h += (uint64_t)(uint32_t)w[8 - n + k] << (8 * k);
      long long sh = (long long)h;       // int64 wraparound semantics
      long long r = sh % (long long)V_;  // trunc-mod to floor-mod
      if (r < 0) r += V_;
      id = (int)r;
    }
    idx[j] = id;
  }
  const int d = (threadIdx.x & 127) * 4;
  float4 acc = *(const float4*)(byte_emb + (size_t)bs[s] * D_ + d);
  #pragma unroll
  for (int j = 0; j < 6; j++) {
    const float4 v = *(const float4*)(ngram_emb + ((size_t)j * V_ + idx[j]) * D_ + d);
    acc.x += v.x; acc.y += v.y; acc.z += v.z; acc.w += v.w;
  }
  const float inv7 = 1.0f / 7.0f;
  f16 t4[4];
  t4[0] = (f16)(acc.x * inv7); t4[1] = (f16)(acc.y * inv7);
  t4[2] = (f16)(acc.z * inv7); t4[3] = (f16)(acc.w * inv7);
  *(uint2*)(out16 + (size_t)pos * D_ + d) = *(uint2*)t4;
}

// ---------------------------------------------------------------------------
// f16 MFMA GEMM body (C^T accumulation), triple-buffered, counted vmcnt,
// conflict-free chunk rotation. Same as round 12.
// ---------------------------------------------------------------------------
template<typename OutT, int RELU, int BN, int VTSTART, int K>
__device__ __forceinline__ void gemm_body(
    const f16* __restrict__ A, const f16* __restrict__ Bt,
    const float* __restrict__ bias, OutT* __restrict__ C,
    int N, const int* __restrict__ rowmap,
    f16* __restrict__ vt, int bmi, int bni, int lda, int ldb)
{
  constexpr int NF = BN / 32;
  constexpr int NT = K / 32;
  constexpr int GL = 2 + BN / 64;
  __shared__ __align__(16) f16 As[3][128 * 32];
  __shared__ __align__(16) f16 Bs[3][BN * 32];
  const int tid = threadIdx.x;
  const int l = tid & 63;
  const int lo4 = l & 15, hi2 = l >> 4;
  const int w = tid >> 6;
  const int wr = w >> 1, wc = w & 1;
  const int bm = bmi * 128, bn = bni * BN;

  const int srot = ((tid & 3) - (tid >> 3)) & 3;

  const f16* ap[2];
  #pragma unroll
  for (int i = 0; i < 2; i++) {
    int r = bm + i * 64 + (tid >> 2);
    int ar = rowmap ? ((r >> 8) * S_ + rowmap[r]) : r;
    ap[i] = A + (size_t)ar * lda + srot * 8;
  }
  const f16* bp[BN / 64];
  #pragma unroll
  for (int i = 0; i < BN / 64; i++) {
    int c = i * 256 + tid;
    bp[i] = Bt + (size_t)(bn + (c >> 2)) * ldb + srot * 8;
  }

  f32x4 acc[4][NF];
  #pragma unroll
  for (int m = 0; m < 4; m++)
    #pragma unroll
    for (int n = 0; n < NF; n++) acc[m][n] = (f32x4){0.f, 0.f, 0.f, 0.f};

  #pragma unroll
  for (int i = 0; i < 2; i++)
    GLDS16(ap[i], &As[0][(i * 256 + tid) * 8]);
  #pragma unroll
  for (int i = 0; i < BN / 64; i++)
    GLDS16(bp[i], &Bs[0][(i * 256 + tid) * 8]);
  #pragma unroll
  for (int i = 0; i < 2; i++)
    GLDS16(ap[i] + 32, &As[1][(i * 256 + tid) * 8]);
  #pragma unroll
  for (int i = 0; i < BN / 64; i++)
    GLDS16(bp[i] + 32, &Bs[1][(i * 256 + tid) * 8]);

  const int rslot = ((hi2 + (lo4 >> 1)) & 3) * 8;

  auto do_mma = [&](int c) {
    f16x8 af[4], bf[NF];
    const f16* pa = &As[c][(wr * 64 + lo4) * 32 + rslot];
    const f16* pb = &Bs[c][(wc * (BN / 2) + lo4) * 32 + rslot];
    #pragma unroll
    for (int m = 0; m < 4; m++) af[m] = *(const f16x8*)(pa + m * 16 * 32);
    #pragma unroll
    for (int n = 0; n < NF; n++) bf[n] = *(const f16x8*)(pb + n * 16 * 32);
    #pragma unroll
    for (int m = 0; m < 4; m++)
      #pragma unroll
      for (int n = 0; n < NF; n++)
        acc[m][n] = MFMA16(bf[n], af[m], acc[m][n]);
  };

  int cur = 0;
  #pragma unroll 3
  for (int t = 0; t < NT - 1; ++t) {
    wait_barrier<GL>();
    if (t + 2 < NT) {
      const int k0 = (t + 2) << 5;
      int stg = cur + 2; if (stg >= 3) stg -= 3;
      #pragma unroll
      for (int i = 0; i < 2; i++)
        GLDS16(ap[i] + k0, &As[stg][(i * 256 + tid) * 8]);
      #pragma unroll
      for (int i = 0; i < BN / 64; i++)
        GLDS16(bp[i] + k0, &Bs[stg][(i * 256 + tid) * 8]);
    }
    do_mma(cur);
    cur = (cur == 2) ? 0 : cur + 1;
  }
  wait_barrier<0>();
  do_mma(cur);

  if constexpr (VTSTART >= 0) {
    if (bn >= VTSTART) {
      #pragma unroll
      for (int n = 0; n < NF; n++) {
        const int col0 = bn + wc * (BN / 2) + n * 16 + hi2 * 4;
        float bb[4] = {0.f, 0.f, 0.f, 0.f};
        if (bias) *(float4*)bb = *(const float4*)(bias + col0);
        #pragma unroll
        for (int m = 0; m < 4; m++) {
          const int s = bm + wr * 64 + m * 16 + lo4;
          #pragma unroll
          for (int j = 0; j < 4; j++) {
            const int dcol = col0 + j - VTSTART;
            vt[(((size_t)(s >> 11) * 8 + (dcol >> 6)) << 17) +
               ((size_t)(dcol & 63) << 11) + (s & 2047)] =
                (f16)(acc[m][n][j] + bb[j]);
          }
        }
      }
      return;
    }
  }

  #pragma unroll
  for (int n = 0; n < NF; n++) {
    const int col0 = bn + wc * (BN / 2) + n * 16 + hi2 * 4;
    float bb[4] = {0.f, 0.f, 0.f, 0.f};
    if (bias) *(float4*)bb = *(const float4*)(bias + col0);
    #pragma unroll
    for (int m = 0; m < 4; m++) {
      const int row = bm + wr * 64 + m * 16 + lo4;
      float v[4];
      #pragma unroll
      for (int j = 0; j < 4; j++) {
        v[j] = acc[m][n][j] + bb[j];
        if (RELU) v[j] = fmaxf(v[j], 0.f);
      }
      if constexpr (sizeof(OutT) == 2) {
        f16 t4[4];
        #pragma unroll
        for (int j = 0; j < 4; j++) t4[j] = (f16)v[j];
        *(uint2*)((f16*)C + (size_t)row * N + col0) = *(uint2*)t4;
      } else {
        float4 t4 = {v[0], v[1], v[2], v[3]};
        *(float4*)((float*)C + (size_t)row * N + col0) = t4;
      }
    }
  }
}

template<typename OutT, int RELU, int BN, int VTSTART, int K>
__global__ __launch_bounds__(256) void gemm_f16(
    const f16* __restrict__ A, const f16* __restrict__ Bt,
    const float* __restrict__ bias, OutT* __restrict__ C,
    int N, const int* __restrict__ rowmap, f16* __restrict__ vt)
{
  gemm_body<OutT, RELU, BN, VTSTART, K>(A, Bt, bias, C, N, rowmap, vt,
                                        blockIdx.x, blockIdx.y, K, K);
}

// ---------------------------------------------------------------------------
// merged cKV GEMM (512 blocks, V^T out) + gather-fused cQ GEMM (64 blocks)
// ---------------------------------------------------------------------------
__global__ __launch_bounds__(256) void ckv_cq_kernel(
    const f16* __restrict__ X, const f16* __restrict__ CKVT,
    const float* __restrict__ bckv, f16* __restrict__ CKV,
    f16* __restrict__ vt2, const f16* __restrict__ cWqT,
    const float* __restrict__ cbq, f16* __restrict__ CQ,
    const int* __restrict__ pidx)
{
  int bid = blockIdx.x;
  if (bid < 512) {
    gemm_body<f16, 0, 128, 512, 512>(X, CKVT, bckv, CKV, 1024,
                                     nullptr, vt2, bid >> 3, bid & 7, 512, 512);
  } else {
    bid -= 512;
    gemm_body<f16, 0, 64, -1, 512>(X, cWqT, cbq, CQ, 512,
                                   pidx, nullptr, bid >> 3, bid & 7, 512, 512);
  }
}

// ---------------------------------------------------------------------------
// final projection, split-K x4
// ---------------------------------------------------------------------------
__global__ __launch_bounds__(256) void co_splitk(
    const f16* __restrict__ A, const f16* __restrict__ Bt,
    float* __restrict__ part)
{
  const int z = blockIdx.z;
  gemm_body<float, 0, 64, -1, 128>(A + z * 128, Bt + z * 128, nullptr,
      part + (size_t)z * NP_ * 512, 512, nullptr, nullptr,
      blockIdx.x, blockIdx.y, 512, 512);
}

__global__ __launch_bounds__(128) void co_reduce(
    const float* __restrict__ part, const float* __restrict__ bias,
    float* __restrict__ out)
{
  const int row = blockIdx.x;
  const int col = threadIdx.x * 4;
  float4 s = *(const float4*)(bias + col);
  #pragma unroll
  for (int c = 0; c < 4; c++) {
    const float4 v = *(const float4*)(part + ((size_t)c * NP_ + row) * 512 + col);
    s.x += v.x; s.y += v.y; s.z += v.z; s.w += v.w;
  }
  *(float4*)(out + (size_t)row * 512 + col) = s;
}

// ---------------------------------------------------------------------------
// f16 MFMA flash attention (same as round 12)
// ---------------------------------------------------------------------------
template<int QG, int CHUNKS>
__global__ __launch_bounds__(256) void attn_f16(
    const f16* __restrict__ Q, int qs,
    const f16* __restrict__ Kp, int kvs,
    const f16* __restrict__ VT, f16* __restrict__ O,
    float* __restrict__ Opart, float* __restrict__ Lpart, int NQ)
{
  constexpr int CL = S_ / CHUNKS;
  constexpr int NT = CL / 64;
  __shared__ __align__(16) f16 Ks[2][64][76];
  __shared__ __align__(16) f16 VtL[2][64 * 64];

  const int tid = threadIdx.x;
  const int w = tid >> 6, l = tid & 63;
  const int lo4 = l & 15, hi2 = l >> 4;
  const int lin = (CHUNKS == 1) ? blockIdx.x : (blockIdx.x & 127);
  const int c   = (CHUNKS == 1) ? 0 : (int)(blockIdx.x >> 7);
  const int h = lin & 7, b = (lin >> 3) & 3, qt = lin >> 5;

  const f16 qscale = (f16)0.18033688f;   // 0.125 * log2(e)
  f16x8 qf[QG][2];
  #pragma unroll
  for (int qg = 0; qg < QG; qg++) {
    const int qrow = qt * (64 * QG) + w * (16 * QG) + qg * 16 + lo4;
    const f16* Qp = Q + (size_t)(b * NQ + qrow) * qs + h * DH_ + hi2 * 8;
    qf[qg][0] = *(const f16x8*)(Qp);
    qf[qg][1] = *(const f16x8*)(Qp + 32);
    #pragma unroll
    for (int i = 0; i < 8; i++) { qf[qg][0][i] *= qscale; qf[qg][1][i] *= qscale; }
  }

  const int g2 = lo4 >> 2, j4 = lo4 & 3;
  const int kvp0 = 8 * g2 + j4;
  const int kvp1 = 8 * (g2 ^ 2) + 4 + j4;
  const int pidx = (l ^ 32) << 2;
  const int vswz = lo4 & 7;

  const f16* Kb = Kp + ((size_t)b * S_ + c * CL) * kvs + h * DH_;
  const f16* VTbh = VT + (((size_t)(b * 8 + h)) << 17) + c * CL;

  float lsum[QG];
  f32x4 oacc[QG][4];
  #pragma unroll
  for (int qg = 0; qg < QG; qg++) {
    lsum[qg] = 0.f;
    #pragma unroll
    for (int df = 0; df < 4; df++) oacc[qg][df] = (f32x4){0.f, 0.f, 0.f, 0.f};
  }

  const int r0 = tid >> 3;
  const int c8 = tid & 7;

  #pragma unroll
  for (int i = 0; i < 2; i++) {
    int r = i * 32 + r0;
    GLDS16(VTbh + (size_t)r * 2048 + ((c8 ^ (r & 7)) * 8), &VtL[0][(i * 256 + tid) * 8]);
  }
  f16x8 kreg[2];
  #pragma unroll
  for (int i = 0; i < 2; i++)
    kreg[i] = *(const f16x8*)(Kb + (size_t)(i * 32 + r0) * kvs + c8 * 8);
  #pragma unroll
  for (int i = 0; i < 2; i++)
    *(f16x8*)(&Ks[0][i * 32 + r0][c8 * 8]) = kreg[i];
  __syncthreads();

  int cur = 0;
  for (int t = 0; t < NT; t++) {
    if (t + 1 < NT) {
      const int kt2 = (t + 1) * 64;
      #pragma unroll
      for (int i = 0; i < 2; i++) {
        int r = i * 32 + r0;
        GLDS16(VTbh + (size_t)r * 2048 + kt2 + ((c8 ^ (r & 7)) * 8),
               &VtL[cur ^ 1][(i * 256 + tid) * 8]);
      }
      #pragma unroll
      for (int i = 0; i < 2; i++)
        kreg[i] = *(const f16x8*)(Kb + (size_t)(kt2 + i * 32 + r0) * kvs + c8 * 8);
    }
    f32x4 sacc[QG][4];
    #pragma unroll
    for (int nf = 0; nf < 4; nf++) {
      const int krow = ((nf & 1) ? kvp1 : kvp0) + (nf >> 1) * 32;
      f16x8 kf0 = *(const f16x8*)(&Ks[cur][krow][hi2 * 8]);
      f16x8 kf1 = *(const f16x8*)(&Ks[cur][krow][32 + hi2 * 8]);
      #pragma unroll
      for (int qg = 0; qg < QG; qg++) {
        f32x4 s = (f32x4){0.f, 0.f, 0.f, 0.f};
        s = MFMA16(kf0, qf[qg][0], s);
        s = MFMA16(kf1, qf[qg][1], s);
        sacc[qg][nf] = s;
      }
    }
    uint32_t packs[QG][4][2];
    #pragma unroll
    for (int qg = 0; qg < QG; qg++)
      #pragma unroll
      for (int nf = 0; nf < 4; nf++) {
        float p0 = exp2f(sacc[qg][nf][0]);
        float p1 = exp2f(sacc[qg][nf][1]);
        float p2 = exp2f(sacc[qg][nf][2]);
        float p3 = exp2f(sacc[qg][nf][3]);
        lsum[qg] += (p0 + p1) + (p2 + p3);
        packs[qg][nf][0] = __builtin_bit_cast(uint32_t, __builtin_amdgcn_cvt_pkrtz(p0, p1));
        packs[qg][nf][1] = __builtin_bit_cast(uint32_t, __builtin_amdgcn_cvt_pkrtz(p2, p3));
      }
    #pragma unroll
    for (int ks = 0; ks < 2; ks++) {
      f16x8 pb[QG];
      #pragma unroll
      for (int qg = 0; qg < QG; qg++) {
        uint32_t w0 = packs[qg][2 * ks][0];
        uint32_t w1 = packs[qg][2 * ks][1];
        uint32_t w2 = (uint32_t)__builtin_amdgcn_ds_bpermute(pidx, (int)packs[qg][2 * ks + 1][0]);
        uint32_t w3 = (uint32_t)__builtin_amdgcn_ds_bpermute(pidx, (int)packs[qg][2 * ks + 1][1]);
        u32x4 bw = (u32x4){w0, w1, w2, w3};
        pb[qg] = __builtin_bit_cast(f16x8, bw);
      }
      #pragma unroll
      for (int df = 0; df < 4; df++) {
        const int r = df * 16 + lo4;
        const int cc = (ks * 4 + hi2) ^ vswz;
        f16x8 vf = *(const f16x8*)(&VtL[cur][r * 64 + cc * 8]);
        #pragma unroll
        for (int qg = 0; qg < QG; qg++)
          oacc[qg][df] = MFMA16(vf, pb[qg], oacc[qg][df]);
      }
    }
    if (t + 1 < NT) {
      #pragma unroll
      for (int i = 0; i < 2; i++)
        *(f16x8*)(&Ks[cur ^ 1][i * 32 + r0][c8 * 8]) = kreg[i];
    }
    __syncthreads();
    cur ^= 1;
  }

  #pragma unroll
  for (int qg = 0; qg < QG; qg++) {
    float r = lsum[qg];
    r += __shfl_xor(r, 16, 64);
    r += __shfl_xor(r, 32, 64);
    const int orow = qt * (64 * QG) + w * (16 * QG) + qg * 16 + lo4;
    if constexpr (CHUNKS == 1) {
      const float invl = 1.0f / r;
      f16* Ob = O + (size_t)(b * NQ + orow) * D_ + h * DH_ + hi2 * 4;
      #pragma unroll
      for (int df = 0; df < 4; df++) {
        f16 t4[4];
        #pragma unroll
        for (int j = 0; j < 4; j++) t4[j] = (f16)(oacc[qg][df][j] * invl);
        *(uint2*)(Ob + df * 16) = *(uint2*)t4;
      }
    } else {
      float* Op = Opart + ((size_t)c * NP_ + b * NQ + orow) * D_ + h * DH_ + hi2 * 4;
      #pragma unroll
      for (int df = 0; df < 4; df++) {
        float4 v = {oacc[qg][df][0], oacc[qg][df][1], oacc[qg][df][2], oacc[qg][df][3]};
        *(float4*)(Op + df * 16) = v;
      }
      if (hi2 == 0)
        Lpart[((size_t)c * NP_ + b * NQ + orow) * H_ + h] = r;
    }
  }
}

// ---------------------------------------------------------------------------
__global__ __launch_bounds__(128) void attn_reduce(
    const float* __restrict__ Opart, const float* __restrict__ Lpart,
    f16* __restrict__ CO)
{
  const int row = blockIdx.x;
  const int col = threadIdx.x * 4;
  const int h = col >> 6;
  float4 o = {0.f, 0.f, 0.f, 0.f};
  float ls = 0.f;
  #pragma unroll
  for (int c = 0; c < 4; c++) {
    const float4 v = *(const float4*)(Opart + ((size_t)c * NP_ + row) * D_ + col);
    o.x += v.x; o.y += v.y; o.z += v.z; o.w += v.w;
    ls += Lpart[((size_t)c * NP_ + row) * H_ + h];
  }
  const float inv = 1.0f / ls;
  f16 t4[4];
  t4[0] = (f16)(o.x * inv); t4[1] = (f16)(o.y * inv);
  t4[2] = (f16)(o.z * inv); t4[3] = (f16)(o.w * inv);
  *(uint2*)(CO + (size_t)row * D_ + col) = *(uint2*)t4;
}

// ---------------------------------------------------------------------------
__global__ __launch_bounds__(256) void ln_kernel(
    const f16* __restrict__ a, const f16* __restrict__ r,
    const float* __restrict__ g, const float* __restrict__ be,
    f16* __restrict__ out)
{
  const int row = blockIdx.x * 2 + (threadIdx.x >> 7);
  const int t = threadIdx.x & 127;
  const f16* ap = a + (size_t)row * D_ + t * 4;
  const f16* rp = r + (size_t)row * D_ + t * 4;
  uint2 au = *(const uint2*)ap, ru = *(const uint2*)rp;
  f16 a4[4], r4[4];
  *(uint2*)a4 = au; *(uint2*)r4 = ru;
  float x0 = (float)a4[0] + (float)r4[0];
  float x1 = (float)a4[1] + (float)r4[1];
  float x2 = (float)a4[2] + (float)r4[2];
  float x3 = (float)a4[3] + (float)r4[3];
  float sm = x0 + x1 + x2 + x3;
  float sq = x0*x0 + x1*x1 + x2*x2 + x3*x3;
  #pragma unroll
  for (int off = 32; off > 0; off >>= 1) {
    sm += __shfl_down(sm, off, 64);
    sq += __shfl_down(sq, off, 64);
  }
  __shared__ float s0[4], s1[4];
  if ((threadIdx.x & 63) == 0) { s0[threadIdx.x >> 6] = sm; s1[threadIdx.x >> 6] = sq; }
  __syncthreads();
  const int base = (threadIdx.x >> 7) * 2;
  const float Sm = s0[base] + s0[base + 1];
  const float Sq = s1[base] + s1[base + 1];
  const float mean = Sm * (1.0f / 512.0f);
  const float var  = Sq * (1.0f / 512.0f) - mean * mean;
  const float inv  = rsqrtf(var + 1e-5f);
  const float4 vg = *(const float4*)(g + t * 4);
  const float4 vb = *(const float4*)(be + t * 4);
  f16 o4[4];
  o4[0] = (f16)(vg.x * (x0 - mean) * inv + vb.x);
  o4[1] = (f16)(vg.y * (x1 - mean) * inv + vb.y);
  o4[2] = (f16)(vg.z * (x2 - mean) * inv + vb.z);
  o4[3] = (f16)(vg.w * (x3 - mean) * inv + vb.w);
  *(uint2*)(out + (size_t)row * D_ + t * 4) = *(uint2*)o4;
}

// ---------------------------------------------------------------------------
extern "C" void kernel_launch(void* const* d_in, const int* in_sizes, int n_in,
                              void* d_out, int out_size, void* d_ws, size_t ws_size,
                              hipStream_t stream) {
  const int*   bytes_seq = (const int*)  d_in[0];
  const int*   patch_idx = (const int*)  d_in[1];
  const float* byte_emb  = (const float*)d_in[2];
  const float* ngram_emb = (const float*)d_in[3];
  const float* sWq = (const float*)d_in[4];  const float* sbq = (const float*)d_in[5];
  const float* sWk = (const float*)d_in[6];  const float* sbk = (const float*)d_in[7];
  const float* sWv = (const float*)d_in[8];  const float* sbv = (const float*)d_in[9];
  const float* sWo = (const float*)d_in[10]; const float* sbo = (const float*)d_in[11];
  const float* ln1g = (const float*)d_in[12]; const float* ln1b = (const float*)d_in[13];
  const float* W1 = (const float*)d_in[14];  const float* b1 = (const float*)d_in[15];
  const float* W2 = (const float*)d_in[16];  const float* b2 = (const float*)d_in[17];
  const float* ln2g = (const float*)d_in[18]; const float* ln2b = (const float*)d_in[19];
  const float* cWq = (const float*)d_in[20]; const float* cbq = (const float*)d_in[21];
  const float* cWk = (const float*)d_in[22]; const float* cbk = (const float*)d_in[23];
  const float* cWv = (const float*)d_in[24]; const float* cbv = (const float*)d_in[25];
  const float* cWo = (const float*)d_in[26]; const float* cbo = (const float*)d_in[27];

  char* base = (char*)d_ws;
  const size_t MB = 1u << 20;
  f16* E16     = (f16*)(base + 0 * MB);
  f16* TMP16   = (f16*)(base + 8 * MB);
  f16* X116    = (f16*)(base + 16 * MB);
  f16* X216    = (f16*)(base + 24 * MB);
  f16* QKV16   = (f16*)(base + 32 * MB);
  f16* AT16    = (f16*)(base + 56 * MB);
  f16* HID16   = (f16*)(base + 64 * MB);
  f16* CKV16   = (f16*)(base + 96 * MB);
  f16* CQ16    = (f16*)(base + 112 * MB);
  f16* CO16    = (f16*)(base + 113 * MB);
  f16* WT      = (f16*)(base + 114 * MB);
  float* bqkv  = (float*)(base + 123 * MB);
  float* bckv  = bqkv + 1536;
  f16* VT      = (f16*)(base + 124 * MB);
  f16* VT2     = (f16*)(base + 132 * MB);
  float* OPART = (float*)(base + 140 * MB);
  float* LPART = (float*)(base + 148 * MB);

  f16* QKVT = WT;
  f16* sWoT = QKVT + 786432;
  f16* W1T  = sWoT + 262144;
  f16* W2T  = W1T + 1048576;
  f16* cWqT = W2T + 1048576;
  f16* CKVT = cWqT + 262144;
  f16* cWoT = CKVT + 524288;

  WJobs wj;
  {
    const float* wsrc[10] = {sWq, sWk, sWv, sWo, W1, W2, cWq, cWk, cWv, cWo};
    f16* wdst[10] = {QKVT, QKVT + 262144, QKVT + 524288, sWoT, W1T, W2T,
                     cWqT, CKVT, CKVT + 262144, cWoT};
    const int wK[10] = {512,512,512,512, 512,2048, 512,512,512,512};
    const int wN[10] = {512,512,512,512, 2048,512, 512,512,512,512};
    for (int i = 0; i < 10; i++) {
      wj.src[i] = wsrc[i]; wj.dst[i] = wdst[i];
      wj.K[i] = wK[i]; wj.N[i] = wN[i];
      wj.tiles[i] = (wK[i] >> 5) * (wN[i] >> 5);
    }
  }

  const dim3 blk256(256), blk128(128);

  prep_kernel<<<10240 + 10 + 4096, blk256, 0, stream>>>(
      wj, sbq, sbk, sbv, cbk, cbv, bqkv, bckv,
      bytes_seq, byte_emb, ngram_emb, E16);

  // ===== MEASUREMENT ROUND: every GEMM-group dispatch is launched TWICE =====
  // (pure functions of their inputs -> identical outputs; dur_new - dur_old
  //  = T_gemm_group + 6 launch overheads, partitioning the 275 us budget)

  gemm_f16<f16, 0, 128, 1024, 512><<<dim3(64, 12), blk256, 0, stream>>>(
      E16, QKVT, bqkv, QKV16, 1536, nullptr, VT);
  gemm_f16<f16, 0, 128, 1024, 512><<<dim3(64, 12), blk256, 0, stream>>>(
      E16, QKVT, bqkv, QKV16, 1536, nullptr, VT);

  attn_f16<2, 1><<<512, blk256, 0, stream>>>(
      QKV16, 1536, QKV16 + 512, 1536, VT, AT16, nullptr, nullptr, S_);

  gemm_f16<f16, 0, 64, -1, 512><<<dim3(64, 8), blk256, 0, stream>>>(
      AT16, sWoT, sbo, TMP16, 512, nullptr, nullptr);
  gemm_f16<f16, 0, 64, -1, 512><<<dim3(64, 8), blk256, 0, stream>>>(
      AT16, sWoT, sbo, TMP16, 512, nullptr, nullptr);
  ln_kernel<<<N_/2, blk256, 0, stream>>>(E16, TMP16, ln1g, ln1b, X116);

  gemm_f16<f16, 1, 128, -1, 512><<<dim3(64, 16), blk256, 0, stream>>>(
      X116, W1T, b1, HID16, 2048, nullptr, nullptr);
  gemm_f16<f16, 1, 128, -1, 512><<<dim3(64, 16), blk256, 0, stream>>>(
      X116, W1T, b1, HID16, 2048, nullptr, nullptr);
  gemm_f16<f16, 0, 64, -1, 2048><<<dim3(64, 8), blk256, 0, stream>>>(
      HID16, W2T, b2, TMP16, 512, nullptr, nullptr);
  gemm_f16<f16, 0, 64, -1, 2048><<<dim3(64, 8), blk256, 0, stream>>>(
      HID16, W2T, b2, TMP16, 512, nullptr, nullptr);
  ln_kernel<<<N_/2, blk256, 0, stream>>>(X116, TMP16, ln2g, ln2b, X216);

  ckv_cq_kernel<<<576, blk256, 0, stream>>>(
      X216, CKVT, bckv, CKV16, VT2, cWqT, cbq, CQ16, patch_idx);
  ckv_cq_kernel<<<576, blk256, 0, stream>>>(
      X216, CKVT, bckv, CKV16, VT2, cWqT, cbq, CQ16, patch_idx);
  attn_f16<1, 4><<<512, blk256, 0, stream>>>(
      CQ16, 512, CKV16, 1024, VT2, nullptr, OPART, LPART, P_);
  attn_reduce<<<NP_, blk128, 0, stream>>>(OPART, LPART, CO16);

  co_splitk<<<dim3(8, 8, 4), blk256, 0, stream>>>(CO16, cWoT, OPART);
  co_splitk<<<dim3(8, 8, 4), blk256, 0, stream>>>(CO16, cWoT, OPART);
  co_reduce<<<NP_, blk128, 0, stream>>>(OPART, cbo, (float*)d_out);
}

// Round 14
// 391.556 us; speedup vs baseline: 1.0566x; 1.0566x over previous
//
#include <hip/hip_runtime.h>
#include <stdint.h>

#define B_   4
#define S_   2048
#define D_   512
#define H_   8
#define DH_  64
#define V_   100000
#define P_   256
#define N_   (B_*S_)    // 8192 rows
#define NP_  (B_*P_)    // 1024 rows

typedef _Float16 f16;
typedef _Float16 f16x8 __attribute__((ext_vector_type(8)));
typedef float    f32x4 __attribute__((ext_vector_type(4)));
typedef uint32_t u32x4 __attribute__((ext_vector_type(4)));

#define MFMA16(a,b,c) __builtin_amdgcn_mfma_f32_16x16x32_f16((a),(b),(c),0,0,0)
#define GLDS16(gp, lp) __builtin_amdgcn_global_load_lds( \
    (const __attribute__((address_space(1))) void*)(gp), \
    (__attribute__((address_space(3))) void*)(lp), 16, 0, 0)

// counted-vmcnt + raw barrier
template<int N>
__device__ __forceinline__ void wait_barrier() {
  if constexpr (N == 0)
    asm volatile("s_waitcnt vmcnt(0)\ns_barrier" ::: "memory");
  else if constexpr (N == 3)
    asm volatile("s_waitcnt vmcnt(3)\ns_barrier" ::: "memory");
  else
    asm volatile("s_waitcnt vmcnt(4)\ns_barrier" ::: "memory");
}

// ---------------------------------------------------------------------------
// Weight-conversion job table
// ---------------------------------------------------------------------------
struct WJobs {
  const float* src[10];
  f16* dst[10];
  int K[10], N[10], tiles[10];
};

// ---------------------------------------------------------------------------
// prep kernel: wconv (10240 blocks) + bias concat (10) + embed (4096, 2 rows)
// ---------------------------------------------------------------------------
__global__ __launch_bounds__(256) void prep_kernel(WJobs jobs,
    const float* __restrict__ sbq, const float* __restrict__ sbk,
    const float* __restrict__ sbv, const float* __restrict__ cbk,
    const float* __restrict__ cbv, float* __restrict__ bqkv,
    float* __restrict__ bckv,
    const int* __restrict__ bytes_seq, const float* __restrict__ byte_emb,
    const float* __restrict__ ngram_emb, f16* __restrict__ out16)
{
  int bid = blockIdx.x;
  if (bid < 10240) {
    const int j = bid >> 10, tile = bid & 1023;
    if (tile >= jobs.tiles[j]) return;
    const int K = jobs.K[j], N = jobs.N[j];
    const int ntiles = N >> 5;
    const int kt = (tile / ntiles) << 5, nt = (tile % ntiles) << 5;
    __shared__ float T[32][33];
    const int t = threadIdx.x;
    const float* src = jobs.src[j];
    #pragma unroll
    for (int p = 0; p < 4; p++) {
      int lin = t + p * 256;
      int rr = lin >> 5, cc = lin & 31;
      T[rr][cc] = src[(size_t)(kt + rr) * N + nt + cc];
    }
    __syncthreads();
    f16* dst = jobs.dst[j];
    #pragma unroll
    for (int p = 0; p < 4; p++) {
      int lin = t + p * 256;
      int rr = lin >> 5, cc = lin & 31;
      dst[(size_t)(nt + rr) * K + kt + cc] = (f16)T[cc][rr];
    }
    return;
  }
  bid -= 10240;
  if (bid < 10) {
    int t = bid * 256 + threadIdx.x;
    if (t < 512)       bqkv[t] = sbq[t];
    else if (t < 1024) bqkv[t] = sbk[t - 512];
    else if (t < 1536) bqkv[t] = sbv[t - 1024];
    else if (t < 2048) bckv[t - 1536] = cbk[t - 1536];
    else if (t < 2560) bckv[t - 1536] = cbv[t - 2048];
    return;
  }
  bid -= 10;
  const int pos = bid * 2 + (threadIdx.x >> 7);
  const int b = pos / S_, s = pos % S_;
  const int* bs = bytes_seq + (size_t)b * S_;

  int w[8];
  #pragma unroll
  for (int k = 0; k < 8; k++) {
    int p = s - 7 + k;
    w[k] = (p >= 0) ? bs[p] : 0;
  }
  int idx[6];
  #pragma unroll
  for (int j = 0; j < 6; j++) {
    const int n = j + 3;
    int id = 0;
    if (s >= n - 1) {
      uint64_t h = 0;
      for (int k = 0; k < n; k++)
        h += (uint64_t)(uint32_t)w[8 - n + k] << (8 * k);
      long long sh = (long long)h;       // int64 wraparound semantics
      long long r = sh % (long long)V_;  // trunc-mod to floor-mod
      if (r < 0) r += V_;
      id = (int)r;
    }
    idx[j] = id;
  }
  const int d = (threadIdx.x & 127) * 4;
  float4 acc = *(const float4*)(byte_emb + (size_t)bs[s] * D_ + d);
  #pragma unroll
  for (int j = 0; j < 6; j++) {
    const float4 v = *(const float4*)(ngram_emb + ((size_t)j * V_ + idx[j]) * D_ + d);
    acc.x += v.x; acc.y += v.y; acc.z += v.z; acc.w += v.w;
  }
  const float inv7 = 1.0f / 7.0f;
  f16 t4[4];
  t4[0] = (f16)(acc.x * inv7); t4[1] = (f16)(acc.y * inv7);
  t4[2] = (f16)(acc.z * inv7); t4[3] = (f16)(acc.w * inv7);
  *(uint2*)(out16 + (size_t)pos * D_ + d) = *(uint2*)t4;
}

// ---------------------------------------------------------------------------
// f16 MFMA GEMM body (C^T accumulation), triple-buffered, counted vmcnt,
// conflict-free chunk rotation. Same as round 12.
// ---------------------------------------------------------------------------
template<typename OutT, int RELU, int BN, int VTSTART, int K>
__device__ __forceinline__ void gemm_body(
    const f16* __restrict__ A, const f16* __restrict__ Bt,
    const float* __restrict__ bias, OutT* __restrict__ C,
    int N, const int* __restrict__ rowmap,
    f16* __restrict__ vt, int bmi, int bni, int lda, int ldb)
{
  constexpr int NF = BN / 32;
  constexpr int NT = K / 32;
  constexpr int GL = 2 + BN / 64;
  __shared__ __align__(16) f16 As[3][128 * 32];
  __shared__ __align__(16) f16 Bs[3][BN * 32];
  const int tid = threadIdx.x;
  const int l = tid & 63;
  const int lo4 = l & 15, hi2 = l >> 4;
  const int w = tid >> 6;
  const int wr = w >> 1, wc = w & 1;
  const int bm = bmi * 128, bn = bni * BN;

  const int srot = ((tid & 3) - (tid >> 3)) & 3;

  const f16* ap[2];
  #pragma unroll
  for (int i = 0; i < 2; i++) {
    int r = bm + i * 64 + (tid >> 2);
    int ar = rowmap ? ((r >> 8) * S_ + rowmap[r]) : r;
    ap[i] = A + (size_t)ar * lda + srot * 8;
  }
  const f16* bp[BN / 64];
  #pragma unroll
  for (int i = 0; i < BN / 64; i++) {
    int c = i * 256 + tid;
    bp[i] = Bt + (size_t)(bn + (c >> 2)) * ldb + srot * 8;
  }

  f32x4 acc[4][NF];
  #pragma unroll
  for (int m = 0; m < 4; m++)
    #pragma unroll
    for (int n = 0; n < NF; n++) acc[m][n] = (f32x4){0.f, 0.f, 0.f, 0.f};

  #pragma unroll
  for (int i = 0; i < 2; i++)
    GLDS16(ap[i], &As[0][(i * 256 + tid) * 8]);
  #pragma unroll
  for (int i = 0; i < BN / 64; i++)
    GLDS16(bp[i], &Bs[0][(i * 256 + tid) * 8]);
  #pragma unroll
  for (int i = 0; i < 2; i++)
    GLDS16(ap[i] + 32, &As[1][(i * 256 + tid) * 8]);
  #pragma unroll
  for (int i = 0; i < BN / 64; i++)
    GLDS16(bp[i] + 32, &Bs[1][(i * 256 + tid) * 8]);

  const int rslot = ((hi2 + (lo4 >> 1)) & 3) * 8;

  auto do_mma = [&](int c) {
    f16x8 af[4], bf[NF];
    const f16* pa = &As[c][(wr * 64 + lo4) * 32 + rslot];
    const f16* pb = &Bs[c][(wc * (BN / 2) + lo4) * 32 + rslot];
    #pragma unroll
    for (int m = 0; m < 4; m++) af[m] = *(const f16x8*)(pa + m * 16 * 32);
    #pragma unroll
    for (int n = 0; n < NF; n++) bf[n] = *(const f16x8*)(pb + n * 16 * 32);
    #pragma unroll
    for (int m = 0; m < 4; m++)
      #pragma unroll
      for (int n = 0; n < NF; n++)
        acc[m][n] = MFMA16(bf[n], af[m], acc[m][n]);
  };

  int cur = 0;
  #pragma unroll 3
  for (int t = 0; t < NT - 1; ++t) {
    wait_barrier<GL>();
    if (t + 2 < NT) {
      const int k0 = (t + 2) << 5;
      int stg = cur + 2; if (stg >= 3) stg -= 3;
      #pragma unroll
      for (int i = 0; i < 2; i++)
        GLDS16(ap[i] + k0, &As[stg][(i * 256 + tid) * 8]);
      #pragma unroll
      for (int i = 0; i < BN / 64; i++)
        GLDS16(bp[i] + k0, &Bs[stg][(i * 256 + tid) * 8]);
    }
    do_mma(cur);
    cur = (cur == 2) ? 0 : cur + 1;
  }
  wait_barrier<0>();
  do_mma(cur);

  if constexpr (VTSTART >= 0) {
    if (bn >= VTSTART) {
      #pragma unroll
      for (int n = 0; n < NF; n++) {
        const int col0 = bn + wc * (BN / 2) + n * 16 + hi2 * 4;
        float bb[4] = {0.f, 0.f, 0.f, 0.f};
        if (bias) *(float4*)bb = *(const float4*)(bias + col0);
        #pragma unroll
        for (int m = 0; m < 4; m++) {
          const int s = bm + wr * 64 + m * 16 + lo4;
          #pragma unroll
          for (int j = 0; j < 4; j++) {
            const int dcol = col0 + j - VTSTART;
            vt[(((size_t)(s >> 11) * 8 + (dcol >> 6)) << 17) +
               ((size_t)(dcol & 63) << 11) + (s & 2047)] =
                (f16)(acc[m][n][j] + bb[j]);
          }
        }
      }
      return;
    }
  }

  #pragma unroll
  for (int n = 0; n < NF; n++) {
    const int col0 = bn + wc * (BN / 2) + n * 16 + hi2 * 4;
    float bb[4] = {0.f, 0.f, 0.f, 0.f};
    if (bias) *(float4*)bb = *(const float4*)(bias + col0);
    #pragma unroll
    for (int m = 0; m < 4; m++) {
      const int row = bm + wr * 64 + m * 16 + lo4;
      float v[4];
      #pragma unroll
      for (int j = 0; j < 4; j++) {
        v[j] = acc[m][n][j] + bb[j];
        if (RELU) v[j] = fmaxf(v[j], 0.f);
      }
      if constexpr (sizeof(OutT) == 2) {
        f16 t4[4];
        #pragma unroll
        for (int j = 0; j < 4; j++) t4[j] = (f16)v[j];
        *(uint2*)((f16*)C + (size_t)row * N + col0) = *(uint2*)t4;
      } else {
        float4 t4 = {v[0], v[1], v[2], v[3]};
        *(float4*)((float*)C + (size_t)row * N + col0) = t4;
      }
    }
  }
}

template<typename OutT, int RELU, int BN, int VTSTART, int K>
__global__ __launch_bounds__(256) void gemm_f16(
    const f16* __restrict__ A, const f16* __restrict__ Bt,
    const float* __restrict__ bias, OutT* __restrict__ C,
    int N, const int* __restrict__ rowmap, f16* __restrict__ vt)
{
  gemm_body<OutT, RELU, BN, VTSTART, K>(A, Bt, bias, C, N, rowmap, vt,
                                        blockIdx.x, blockIdx.y, K, K);
}

// ---------------------------------------------------------------------------
// merged cKV GEMM (512 blocks, V^T out) + gather-fused cQ GEMM (64 blocks)
// ---------------------------------------------------------------------------
__global__ __launch_bounds__(256) void ckv_cq_kernel(
    const f16* __restrict__ X, const f16* __restrict__ CKVT,
    const float* __restrict__ bckv, f16* __restrict__ CKV,
    f16* __restrict__ vt2, const f16* __restrict__ cWqT,
    const float* __restrict__ cbq, f16* __restrict__ CQ,
    const int* __restrict__ pidx)
{
  int bid = blockIdx.x;
  if (bid < 512) {
    gemm_body<f16, 0, 128, 512, 512>(X, CKVT, bckv, CKV, 1024,
                                     nullptr, vt2, bid >> 3, bid & 7, 512, 512);
  } else {
    bid -= 512;
    gemm_body<f16, 0, 64, -1, 512>(X, cWqT, cbq, CQ, 512,
                                   pidx, nullptr, bid >> 3, bid & 7, 512, 512);
  }
}

// ---------------------------------------------------------------------------
// final projection, split-K x4
// ---------------------------------------------------------------------------
__global__ __launch_bounds__(256) void co_splitk(
    const f16* __restrict__ A, const f16* __restrict__ Bt,
    float* __restrict__ part)
{
  const int z = blockIdx.z;
  gemm_body<float, 0, 64, -1, 128>(A + z * 128, Bt + z * 128, nullptr,
      part + (size_t)z * NP_ * 512, 512, nullptr, nullptr,
      blockIdx.x, blockIdx.y, 512, 512);
}

__global__ __launch_bounds__(128) void co_reduce(
    const float* __restrict__ part, const float* __restrict__ bias,
    float* __restrict__ out)
{
  const int row = blockIdx.x;
  const int col = threadIdx.x * 4;
  float4 s = *(const float4*)(bias + col);
  #pragma unroll
  for (int c = 0; c < 4; c++) {
    const float4 v = *(const float4*)(part + ((size_t)c * NP_ + row) * 512 + col);
    s.x += v.x; s.y += v.y; s.z += v.z; s.w += v.w;
  }
  *(float4*)(out + (size_t)row * 512 + col) = s;
}

// ---------------------------------------------------------------------------
// f16 MFMA flash attention (same as round 12)
// ---------------------------------------------------------------------------
template<int QG, int CHUNKS>
__global__ __launch_bounds__(256) void attn_f16(
    const f16* __restrict__ Q, int qs,
    const f16* __restrict__ Kp, int kvs,
    const f16* __restrict__ VT, f16* __restrict__ O,
    float* __restrict__ Opart, float* __restrict__ Lpart, int NQ)
{
  constexpr int CL = S_ / CHUNKS;
  constexpr int NT = CL / 64;
  __shared__ __align__(16) f16 Ks[2][64][76];
  __shared__ __align__(16) f16 VtL[2][64 * 64];

  const int tid = threadIdx.x;
  const int w = tid >> 6, l = tid & 63;
  const int lo4 = l & 15, hi2 = l >> 4;
  const int lin = (CHUNKS == 1) ? blockIdx.x : (blockIdx.x & 127);
  const int c   = (CHUNKS == 1) ? 0 : (int)(blockIdx.x >> 7);
  const int h = lin & 7, b = (lin >> 3) & 3, qt = lin >> 5;

  const f16 qscale = (f16)0.18033688f;   // 0.125 * log2(e)
  f16x8 qf[QG][2];
  #pragma unroll
  for (int qg = 0; qg < QG; qg++) {
    const int qrow = qt * (64 * QG) + w * (16 * QG) + qg * 16 + lo4;
    const f16* Qp = Q + (size_t)(b * NQ + qrow) * qs + h * DH_ + hi2 * 8;
    qf[qg][0] = *(const f16x8*)(Qp);
    qf[qg][1] = *(const f16x8*)(Qp + 32);
    #pragma unroll
    for (int i = 0; i < 8; i++) { qf[qg][0][i] *= qscale; qf[qg][1][i] *= qscale; }
  }

  const int g2 = lo4 >> 2, j4 = lo4 & 3;
  const int kvp0 = 8 * g2 + j4;
  const int kvp1 = 8 * (g2 ^ 2) + 4 + j4;
  const int pidx = (l ^ 32) << 2;
  const int vswz = lo4 & 7;

  const f16* Kb = Kp + ((size_t)b * S_ + c * CL) * kvs + h * DH_;
  const f16* VTbh = VT + (((size_t)(b * 8 + h)) << 17) + c * CL;

  float lsum[QG];
  f32x4 oacc[QG][4];
  #pragma unroll
  for (int qg = 0; qg < QG; qg++) {
    lsum[qg] = 0.f;
    #pragma unroll
    for (int df = 0; df < 4; df++) oacc[qg][df] = (f32x4){0.f, 0.f, 0.f, 0.f};
  }

  const int r0 = tid >> 3;
  const int c8 = tid & 7;

  #pragma unroll
  for (int i = 0; i < 2; i++) {
    int r = i * 32 + r0;
    GLDS16(VTbh + (size_t)r * 2048 + ((c8 ^ (r & 7)) * 8), &VtL[0][(i * 256 + tid) * 8]);
  }
  f16x8 kreg[2];
  #pragma unroll
  for (int i = 0; i < 2; i++)
    kreg[i] = *(const f16x8*)(Kb + (size_t)(i * 32 + r0) * kvs + c8 * 8);
  #pragma unroll
  for (int i = 0; i < 2; i++)
    *(f16x8*)(&Ks[0][i * 32 + r0][c8 * 8]) = kreg[i];
  __syncthreads();

  int cur = 0;
  for (int t = 0; t < NT; t++) {
    if (t + 1 < NT) {
      const int kt2 = (t + 1) * 64;
      #pragma unroll
      for (int i = 0; i < 2; i++) {
        int r = i * 32 + r0;
        GLDS16(VTbh + (size_t)r * 2048 + kt2 + ((c8 ^ (r & 7)) * 8),
               &VtL[cur ^ 1][(i * 256 + tid) * 8]);
      }
      #pragma unroll
      for (int i = 0; i < 2; i++)
        kreg[i] = *(const f16x8*)(Kb + (size_t)(kt2 + i * 32 + r0) * kvs + c8 * 8);
    }
    f32x4 sacc[QG][4];
    #pragma unroll
    for (int nf = 0; nf < 4; nf++) {
      const int krow = ((nf & 1) ? kvp1 : kvp0) + (nf >> 1) * 32;
      f16x8 kf0 = *(const f16x8*)(&Ks[cur][krow][hi2 * 8]);
      f16x8 kf1 = *(const f16x8*)(&Ks[cur][krow][32 + hi2 * 8]);
      #pragma unroll
      for (int qg = 0; qg < QG; qg++) {
        f32x4 s = (f32x4){0.f, 0.f, 0.f, 0.f};
        s = MFMA16(kf0, qf[qg][0], s);
        s = MFMA16(kf1, qf[qg][1], s);
        sacc[qg][nf] = s;
      }
    }
    uint32_t packs[QG][4][2];
    #pragma unroll
    for (int qg = 0; qg < QG; qg++)
      #pragma unroll
      for (int nf = 0; nf < 4; nf++) {
        float p0 = exp2f(sacc[qg][nf][0]);
        float p1 = exp2f(sacc[qg][nf][1]);
        float p2 = exp2f(sacc[qg][nf][2]);
        float p3 = exp2f(sacc[qg][nf][3]);
        lsum[qg] += (p0 + p1) + (p2 + p3);
        packs[qg][nf][0] = __builtin_bit_cast(uint32_t, __builtin_amdgcn_cvt_pkrtz(p0, p1));
        packs[qg][nf][1] = __builtin_bit_cast(uint32_t, __builtin_amdgcn_cvt_pkrtz(p2, p3));
      }
    #pragma unroll
    for (int ks = 0; ks < 2; ks++) {
      f16x8 pb[QG];
      #pragma unroll
      for (int qg = 0; qg < QG; qg++) {
        uint32_t w0 = packs[qg][2 * ks][0];
        uint32_t w1 = packs[qg][2 * ks][1];
        uint32_t w2 = (uint32_t)__builtin_amdgcn_ds_bpermute(pidx, (int)packs[qg][2 * ks + 1][0]);
        uint32_t w3 = (uint32_t)__builtin_amdgcn_ds_bpermute(pidx, (int)packs[qg][2 * ks + 1][1]);
        u32x4 bw = (u32x4){w0, w1, w2, w3};
        pb[qg] = __builtin_bit_cast(f16x8, bw);
      }
      #pragma unroll
      for (int df = 0; df < 4; df++) {
        const int r = df * 16 + lo4;
        const int cc = (ks * 4 + hi2) ^ vswz;
        f16x8 vf = *(const f16x8*)(&VtL[cur][r * 64 + cc * 8]);
        #pragma unroll
        for (int qg = 0; qg < QG; qg++)
          oacc[qg][df] = MFMA16(vf, pb[qg], oacc[qg][df]);
      }
    }
    if (t + 1 < NT) {
      #pragma unroll
      for (int i = 0; i < 2; i++)
        *(f16x8*)(&Ks[cur ^ 1][i * 32 + r0][c8 * 8]) = kreg[i];
    }
    __syncthreads();
    cur ^= 1;
  }

  #pragma unroll
  for (int qg = 0; qg < QG; qg++) {
    float r = lsum[qg];
    r += __shfl_xor(r, 16, 64);
    r += __shfl_xor(r, 32, 64);
    const int orow = qt * (64 * QG) + w * (16 * QG) + qg * 16 + lo4;
    if constexpr (CHUNKS == 1) {
      const float invl = 1.0f / r;
      f16* Ob = O + (size_t)(b * NQ + orow) * D_ + h * DH_ + hi2 * 4;
      #pragma unroll
      for (int df = 0; df < 4; df++) {
        f16 t4[4];
        #pragma unroll
        for (int j = 0; j < 4; j++) t4[j] = (f16)(oacc[qg][df][j] * invl);
        *(uint2*)(Ob + df * 16) = *(uint2*)t4;
      }
    } else {
      float* Op = Opart + ((size_t)c * NP_ + b * NQ + orow) * D_ + h * DH_ + hi2 * 4;
      #pragma unroll
      for (int df = 0; df < 4; df++) {
        float4 v = {oacc[qg][df][0], oacc[qg][df][1], oacc[qg][df][2], oacc[qg][df][3]};
        *(float4*)(Op + df * 16) = v;
      }
      if (hi2 == 0)
        Lpart[((size_t)c * NP_ + b * NQ + orow) * H_ + h] = r;
    }
  }
}

// ---------------------------------------------------------------------------
__global__ __launch_bounds__(128) void attn_reduce(
    const float* __restrict__ Opart, const float* __restrict__ Lpart,
    f16* __restrict__ CO)
{
  const int row = blockIdx.x;
  const int col = threadIdx.x * 4;
  const int h = col >> 6;
  float4 o = {0.f, 0.f, 0.f, 0.f};
  float ls = 0.f;
  #pragma unroll
  for (int c = 0; c < 4; c++) {
    const float4 v = *(const float4*)(Opart + ((size_t)c * NP_ + row) * D_ + col);
    o.x += v.x; o.y += v.y; o.z += v.z; o.w += v.w;
    ls += Lpart[((size_t)c * NP_ + row) * H_ + h];
  }
  const float inv = 1.0f / ls;
  f16 t4[4];
  t4[0] = (f16)(o.x * inv); t4[1] = (f16)(o.y * inv);
  t4[2] = (f16)(o.z * inv); t4[3] = (f16)(o.w * inv);
  *(uint2*)(CO + (size_t)row * D_ + col) = *(uint2*)t4;
}

// ---------------------------------------------------------------------------
__global__ __launch_bounds__(256) void ln_kernel(
    const f16* __restrict__ a, const f16* __restrict__ r,
    const float* __restrict__ g, const float* __restrict__ be,
    f16* __restrict__ out)
{
  const int row = blockIdx.x * 2 + (threadIdx.x >> 7);
  const int t = threadIdx.x & 127;
  const f16* ap = a + (size_t)row * D_ + t * 4;
  const f16* rp = r + (size_t)row * D_ + t * 4;
  uint2 au = *(const uint2*)ap, ru = *(const uint2*)rp;
  f16 a4[4], r4[4];
  *(uint2*)a4 = au; *(uint2*)r4 = ru;
  float x0 = (float)a4[0] + (float)r4[0];
  float x1 = (float)a4[1] + (float)r4[1];
  float x2 = (float)a4[2] + (float)r4[2];
  float x3 = (float)a4[3] + (float)r4[3];
  float sm = x0 + x1 + x2 + x3;
  float sq = x0*x0 + x1*x1 + x2*x2 + x3*x3;
  #pragma unroll
  for (int off = 32; off > 0; off >>= 1) {
    sm += __shfl_down(sm, off, 64);
    sq += __shfl_down(sq, off, 64);
  }
  __shared__ float s0[4], s1[4];
  if ((threadIdx.x & 63) == 0) { s0[threadIdx.x >> 6] = sm; s1[threadIdx.x >> 6] = sq; }
  __syncthreads();
  const int base = (threadIdx.x >> 7) * 2;
  const float Sm = s0[base] + s0[base + 1];
  const float Sq = s1[base] + s1[base + 1];
  const float mean = Sm * (1.0f / 512.0f);
  const float var  = Sq * (1.0f / 512.0f) - mean * mean;
  const float inv  = rsqrtf(var + 1e-5f);
  const float4 vg = *(const float4*)(g + t * 4);
  const float4 vb = *(const float4*)(be + t * 4);
  f16 o4[4];
  o4[0] = (f16)(vg.x * (x0 - mean) * inv + vb.x);
  o4[1] = (f16)(vg.y * (x1 - mean) * inv + vb.y);
  o4[2] = (f16)(vg.z * (x2 - mean) * inv + vb.z);
  o4[3] = (f16)(vg.w * (x3 - mean) * inv + vb.w);
  *(uint2*)(out + (size_t)row * D_ + t * 4) = *(uint2*)o4;
}

// ---------------------------------------------------------------------------
extern "C" void kernel_launch(void* const* d_in, const int* in_sizes, int n_in,
                              void* d_out, int out_size, void* d_ws, size_t ws_size,
                              hipStream_t stream) {
  const int*   bytes_seq = (const int*)  d_in[0];
  const int*   patch_idx = (const int*)  d_in[1];
  const float* byte_emb  = (const float*)d_in[2];
  const float* ngram_emb = (const float*)d_in[3];
  const float* sWq = (const float*)d_in[4];  const float* sbq = (const float*)d_in[5];
  const float* sWk = (const float*)d_in[6];  const float* sbk = (const float*)d_in[7];
  const float* sWv = (const float*)d_in[8];  const float* sbv = (const float*)d_in[9];
  const float* sWo = (const float*)d_in[10]; const float* sbo = (const float*)d_in[11];
  const float* ln1g = (const float*)d_in[12]; const float* ln1b = (const float*)d_in[13];
  const float* W1 = (const float*)d_in[14];  const float* b1 = (const float*)d_in[15];
  const float* W2 = (const float*)d_in[16];  const float* b2 = (const float*)d_in[17];
  const float* ln2g = (const float*)d_in[18]; const float* ln2b = (const float*)d_in[19];
  const float* cWq = (const float*)d_in[20]; const float* cbq = (const float*)d_in[21];
  const float* cWk = (const float*)d_in[22]; const float* cbk = (const float*)d_in[23];
  const float* cWv = (const float*)d_in[24]; const float* cbv = (const float*)d_in[25];
  const float* cWo = (const float*)d_in[26]; const float* cbo = (const float*)d_in[27];

  char* base = (char*)d_ws;
  const size_t MB = 1u << 20;
  f16* E16     = (f16*)(base + 0 * MB);
  f16* TMP16   = (f16*)(base + 8 * MB);
  f16* X116    = (f16*)(base + 16 * MB);
  f16* X216    = (f16*)(base + 24 * MB);
  f16* QKV16   = (f16*)(base + 32 * MB);
  f16* AT16    = (f16*)(base + 56 * MB);
  f16* HID16   = (f16*)(base + 64 * MB);
  f16* CKV16   = (f16*)(base + 96 * MB);
  f16* CQ16    = (f16*)(base + 112 * MB);
  f16* CO16    = (f16*)(base + 113 * MB);
  f16* WT      = (f16*)(base + 114 * MB);
  float* bqkv  = (float*)(base + 123 * MB);
  float* bckv  = bqkv + 1536;
  f16* VT      = (f16*)(base + 124 * MB);
  f16* VT2     = (f16*)(base + 132 * MB);
  float* OPART = (float*)(base + 140 * MB);
  float* LPART = (float*)(base + 148 * MB);

  f16* QKVT = WT;
  f16* sWoT = QKVT + 786432;
  f16* W1T  = sWoT + 262144;
  f16* W2T  = W1T + 1048576;
  f16* cWqT = W2T + 1048576;
  f16* CKVT = cWqT + 262144;
  f16* cWoT = CKVT + 524288;

  WJobs wj;
  {
    const float* wsrc[10] = {sWq, sWk, sWv, sWo, W1, W2, cWq, cWk, cWv, cWo};
    f16* wdst[10] = {QKVT, QKVT + 262144, QKVT + 524288, sWoT, W1T, W2T,
                     cWqT, CKVT, CKVT + 262144, cWoT};
    const int wK[10] = {512,512,512,512, 512,2048, 512,512,512,512};
    const int wN[10] = {512,512,512,512, 2048,512, 512,512,512,512};
    for (int i = 0; i < 10; i++) {
      wj.src[i] = wsrc[i]; wj.dst[i] = wdst[i];
      wj.K[i] = wK[i]; wj.N[i] = wN[i];
      wj.tiles[i] = (wK[i] >> 5) * (wN[i] >> 5);
    }
  }

  const dim3 blk256(256), blk128(128);

  // ===== MEASUREMENT ROUND 2: every NON-GEMM dispatch is launched TWICE =====
  // (all pure functions of their inputs -> identical outputs; dur - 275
  //  = T_nongemm + 7 launch overheads, completing the budget partition)

  prep_kernel<<<10240 + 10 + 4096, blk256, 0, stream>>>(
      wj, sbq, sbk, sbv, cbk, cbv, bqkv, bckv,
      bytes_seq, byte_emb, ngram_emb, E16);
  prep_kernel<<<10240 + 10 + 4096, blk256, 0, stream>>>(
      wj, sbq, sbk, sbv, cbk, cbv, bqkv, bckv,
      bytes_seq, byte_emb, ngram_emb, E16);

  gemm_f16<f16, 0, 128, 1024, 512><<<dim3(64, 12), blk256, 0, stream>>>(
      E16, QKVT, bqkv, QKV16, 1536, nullptr, VT);

  attn_f16<2, 1><<<512, blk256, 0, stream>>>(
      QKV16, 1536, QKV16 + 512, 1536, VT, AT16, nullptr, nullptr, S_);
  attn_f16<2, 1><<<512, blk256, 0, stream>>>(
      QKV16, 1536, QKV16 + 512, 1536, VT, AT16, nullptr, nullptr, S_);

  gemm_f16<f16, 0, 64, -1, 512><<<dim3(64, 8), blk256, 0, stream>>>(
      AT16, sWoT, sbo, TMP16, 512, nullptr, nullptr);
  ln_kernel<<<N_/2, blk256, 0, stream>>>(E16, TMP16, ln1g, ln1b, X116);
  ln_kernel<<<N_/2, blk256, 0, stream>>>(E16, TMP16, ln1g, ln1b, X116);

  gemm_f16<f16, 1, 128, -1, 512><<<dim3(64, 16), blk256, 0, stream>>>(
      X116, W1T, b1, HID16, 2048, nullptr, nullptr);
  gemm_f16<f16, 0, 64, -1, 2048><<<dim3(64, 8), blk256, 0, stream>>>(
      HID16, W2T, b2, TMP16, 512, nullptr, nullptr);
  ln_kernel<<<N_/2, blk256, 0, stream>>>(X116, TMP16, ln2g, ln2b, X216);
  ln_kernel<<<N_/2, blk256, 0, stream>>>(X116, TMP16, ln2g, ln2b, X216);

  ckv_cq_kernel<<<576, blk256, 0, stream>>>(
      X216, CKVT, bckv, CKV16, VT2, cWqT, cbq, CQ16, patch_idx);
  attn_f16<1, 4><<<512, blk256, 0, stream>>>(
      CQ16, 512, CKV16, 1024, VT2, nullptr, OPART, LPART, P_);
  attn_f16<1, 4><<<512, blk256, 0, stream>>>(
      CQ16, 512, CKV16, 1024, VT2, nullptr, OPART, LPART, P_);
  attn_reduce<<<NP_, blk128, 0, stream>>>(OPART, LPART, CO16);
  attn_reduce<<<NP_, blk128, 0, stream>>>(OPART, LPART, CO16);

  co_splitk<<<dim3(8, 8, 4), blk256, 0, stream>>>(CO16, cWoT, OPART);
  co_reduce<<<NP_, blk128, 0, stream>>>(OPART, cbo, (float*)d_out);
  co_reduce<<<NP_, blk128, 0, stream>>>(OPART, cbo, (float*)d_out);
}

// Round 15
// 274.756 us; speedup vs baseline: 1.5058x; 1.4251x over previous
//
#include <hip/hip_runtime.h>
#include <stdint.h>

#define B_   4
#define S_   2048
#define D_   512
#define H_   8
#define DH_  64
#define V_   100000
#define P_   256
#define N_   (B_*S_)    // 8192 rows
#define NP_  (B_*P_)    // 1024 rows

typedef _Float16 f16;
typedef _Float16 f16x8 __attribute__((ext_vector_type(8)));
typedef float    f32x4 __attribute__((ext_vector_type(4)));
typedef uint32_t u32x4 __attribute__((ext_vector_type(4)));

#define MFMA16(a,b,c) __builtin_amdgcn_mfma_f32_16x16x32_f16((a),(b),(c),0,0,0)
#define GLDS16(gp, lp) __builtin_amdgcn_global_load_lds( \
    (const __attribute__((address_space(1))) void*)(gp), \
    (__attribute__((address_space(3))) void*)(lp), 16, 0, 0)

// counted-vmcnt + raw barrier
template<int N>
__device__ __forceinline__ void wait_barrier() {
  if constexpr (N == 0)
    asm volatile("s_waitcnt vmcnt(0)\ns_barrier" ::: "memory");
  else if constexpr (N == 3)
    asm volatile("s_waitcnt vmcnt(3)\ns_barrier" ::: "memory");
  else
    asm volatile("s_waitcnt vmcnt(4)\ns_barrier" ::: "memory");
}

// ---------------------------------------------------------------------------
// Weight-conversion job table
// ---------------------------------------------------------------------------
struct WJobs {
  const float* src[10];
  f16* dst[10];
  int K[10], N[10], tiles[10];
};

// ---------------------------------------------------------------------------
// prep kernel: wconv (10240 blocks) + bias concat (10) + embed (4096, 2 rows)
// ---------------------------------------------------------------------------
__global__ __launch_bounds__(256) void prep_kernel(WJobs jobs,
    const float* __restrict__ sbq, const float* __restrict__ sbk,
    const float* __restrict__ sbv, const float* __restrict__ cbk,
    const float* __restrict__ cbv, float* __restrict__ bqkv,
    float* __restrict__ bckv,
    const int* __restrict__ bytes_seq, const float* __restrict__ byte_emb,
    const float* __restrict__ ngram_emb, f16* __restrict__ out16)
{
  int bid = blockIdx.x;
  if (bid < 10240) {
    const int j = bid >> 10, tile = bid & 1023;
    if (tile >= jobs.tiles[j]) return;
    const int K = jobs.K[j], N = jobs.N[j];
    const int ntiles = N >> 5;
    const int kt = (tile / ntiles) << 5, nt = (tile % ntiles) << 5;
    __shared__ float T[32][33];
    const int t = threadIdx.x;
    const float* src = jobs.src[j];
    #pragma unroll
    for (int p = 0; p < 4; p++) {
      int lin = t + p * 256;
      int rr = lin >> 5, cc = lin & 31;
      T[rr][cc] = src[(size_t)(kt + rr) * N + nt + cc];
    }
    __syncthreads();
    f16* dst = jobs.dst[j];
    #pragma unroll
    for (int p = 0; p < 4; p++) {
      int lin = t + p * 256;
      int rr = lin >> 5, cc = lin & 31;
      dst[(size_t)(nt + rr) * K + kt + cc] = (f16)T[cc][rr];
    }
    return;
  }
  bid -= 10240;
  if (bid < 10) {
    int t = bid * 256 + threadIdx.x;
    if (t < 512)       bqkv[t] = sbq[t];
    else if (t < 1024) bqkv[t] = sbk[t - 512];
    else if (t < 1536) bqkv[t] = sbv[t - 1024];
    else if (t < 2048) bckv[t - 1536] = cbk[t - 1536];
    else if (t < 2560) bckv[t - 1536] = cbv[t - 2048];
    return;
  }
  bid -= 10;
  const int pos = bid * 2 + (threadIdx.x >> 7);
  const int b = pos / S_, s = pos % S_;
  const int* bs = bytes_seq + (size_t)b * S_;

  int w[8];
  #pragma unroll
  for (int k = 0; k < 8; k++) {
    int p = s - 7 + k;
    w[k] = (p >= 0) ? bs[p] : 0;
  }
  int idx[6];
  #pragma unroll
  for (int j = 0; j < 6; j++) {
    const int n = j + 3;
    int id = 0;
    if (s >= n - 1) {
      uint64_t h = 0;
      for (int k = 0; k < n; k++)
        h += (uint64_t)(uint32_t)w[8 - n + k] << (8 * k);
      long long sh = (long long)h;       // int64 wraparound semantics
      long long r = sh % (long long)V_;  // trunc-mod to floor-mod
      if (r < 0) r += V_;
      id = (int)r;
    }
    idx[j] = id;
  }
  const int d = (threadIdx.x & 127) * 4;
  float4 acc = *(const float4*)(byte_emb + (size_t)bs[s] * D_ + d);
  #pragma unroll
  for (int j = 0; j < 6; j++) {
    const float4 v = *(const float4*)(ngram_emb + ((size_t)j * V_ + idx[j]) * D_ + d);
    acc.x += v.x; acc.y += v.y; acc.z += v.z; acc.w += v.w;
  }
  const float inv7 = 1.0f / 7.0f;
  f16 t4[4];
  t4[0] = (f16)(acc.x * inv7); t4[1] = (f16)(acc.y * inv7);
  t4[2] = (f16)(acc.z * inv7); t4[3] = (f16)(acc.w * inv7);
  *(uint2*)(out16 + (size_t)pos * D_ + d) = *(uint2*)t4;
}

// ---------------------------------------------------------------------------
// f16 MFMA GEMM body (C^T accumulation), triple-buffered, counted vmcnt,
// conflict-free chunk rotation. Generic over BM (128: 4 waves / 256: 8 waves,
// per-wave work identical). BM=256 halves A-panel staging traffic.
// ---------------------------------------------------------------------------
template<typename OutT, int RELU, int BM, int BN, int VTSTART, int K>
__device__ __forceinline__ void gemm_body(
    const f16* __restrict__ A, const f16* __restrict__ Bt,
    const float* __restrict__ bias, OutT* __restrict__ C,
    int N, const int* __restrict__ rowmap,
    f16* __restrict__ vt, int bmi, int bni, int lda, int ldb)
{
  constexpr int THREADS = BM * 2;
  constexpr int NF = BN / 32;           // N-frags per wave
  constexpr int NT = K / 32;            // K-steps
  constexpr int BP = (BN * 4) / THREADS;   // B GLDS per thread
  constexpr int GL = 2 + BP;               // GLDS per thread per tile
  __shared__ __align__(16) f16 As[3][BM * 32];
  __shared__ __align__(16) f16 Bs[3][BN * 32];
  const int tid = threadIdx.x;
  const int l = tid & 63;
  const int lo4 = l & 15, hi2 = l >> 4;
  const int w = tid >> 6;
  const int wr = w >> 1, wc = w & 1;
  const int bm = bmi * BM, bn = bni * BN;

  const int srot = ((tid & 3) - (tid >> 3)) & 3;

  const f16* ap[2];
  #pragma unroll
  for (int i = 0; i < 2; i++) {
    int r = bm + i * (THREADS / 4) + (tid >> 2);
    int ar = rowmap ? ((r >> 8) * S_ + rowmap[r]) : r;
    ap[i] = A + (size_t)ar * lda + srot * 8;
  }
  const f16* bp[BP];
  #pragma unroll
  for (int i = 0; i < BP; i++) {
    int c = i * THREADS + tid;
    bp[i] = Bt + (size_t)(bn + (c >> 2)) * ldb + srot * 8;
  }

  f32x4 acc[4][NF];
  #pragma unroll
  for (int m = 0; m < 4; m++)
    #pragma unroll
    for (int n = 0; n < NF; n++) acc[m][n] = (f32x4){0.f, 0.f, 0.f, 0.f};

  #pragma unroll
  for (int i = 0; i < 2; i++)
    GLDS16(ap[i], &As[0][(i * THREADS + tid) * 8]);
  #pragma unroll
  for (int i = 0; i < BP; i++)
    GLDS16(bp[i], &Bs[0][(i * THREADS + tid) * 8]);
  #pragma unroll
  for (int i = 0; i < 2; i++)
    GLDS16(ap[i] + 32, &As[1][(i * THREADS + tid) * 8]);
  #pragma unroll
  for (int i = 0; i < BP; i++)
    GLDS16(bp[i] + 32, &Bs[1][(i * THREADS + tid) * 8]);

  const int rslot = ((hi2 + (lo4 >> 1)) & 3) * 8;

  auto do_mma = [&](int c) {
    f16x8 af[4], bf[NF];
    const f16* pa = &As[c][(wr * 64 + lo4) * 32 + rslot];
    const f16* pb = &Bs[c][(wc * (BN / 2) + lo4) * 32 + rslot];
    #pragma unroll
    for (int m = 0; m < 4; m++) af[m] = *(const f16x8*)(pa + m * 16 * 32);
    #pragma unroll
    for (int n = 0; n < NF; n++) bf[n] = *(const f16x8*)(pb + n * 16 * 32);
    #pragma unroll
    for (int m = 0; m < 4; m++)
      #pragma unroll
      for (int n = 0; n < NF; n++)
        acc[m][n] = MFMA16(bf[n], af[m], acc[m][n]);
  };

  int cur = 0;
  #pragma unroll 3
  for (int t = 0; t < NT - 1; ++t) {
    wait_barrier<GL>();
    if (t + 2 < NT) {
      const int k0 = (t + 2) << 5;
      int stg = cur + 2; if (stg >= 3) stg -= 3;
      #pragma unroll
      for (int i = 0; i < 2; i++)
        GLDS16(ap[i] + k0, &As[stg][(i * THREADS + tid) * 8]);
      #pragma unroll
      for (int i = 0; i < BP; i++)
        GLDS16(bp[i] + k0, &Bs[stg][(i * THREADS + tid) * 8]);
    }
    do_mma(cur);
    cur = (cur == 2) ? 0 : cur + 1;
  }
  wait_barrier<0>();
  do_mma(cur);

  if constexpr (VTSTART >= 0) {
    if (bn >= VTSTART) {
      #pragma unroll
      for (int n = 0; n < NF; n++) {
        const int col0 = bn + wc * (BN / 2) + n * 16 + hi2 * 4;
        float bb[4] = {0.f, 0.f, 0.f, 0.f};
        if (bias) *(float4*)bb = *(const float4*)(bias + col0);
        #pragma unroll
        for (int m = 0; m < 4; m++) {
          const int s = bm + wr * 64 + m * 16 + lo4;
          #pragma unroll
          for (int j = 0; j < 4; j++) {
            const int dcol = col0 + j - VTSTART;
            vt[(((size_t)(s >> 11) * 8 + (dcol >> 6)) << 17) +
               ((size_t)(dcol & 63) << 11) + (s & 2047)] =
                (f16)(acc[m][n][j] + bb[j]);
          }
        }
      }
      return;
    }
  }

  #pragma unroll
  for (int n = 0; n < NF; n++) {
    const int col0 = bn + wc * (BN / 2) + n * 16 + hi2 * 4;
    float bb[4] = {0.f, 0.f, 0.f, 0.f};
    if (bias) *(float4*)bb = *(const float4*)(bias + col0);
    #pragma unroll
    for (int m = 0; m < 4; m++) {
      const int row = bm + wr * 64 + m * 16 + lo4;
      float v[4];
      #pragma unroll
      for (int j = 0; j < 4; j++) {
        v[j] = acc[m][n][j] + bb[j];
        if (RELU) v[j] = fmaxf(v[j], 0.f);
      }
      if constexpr (sizeof(OutT) == 2) {
        f16 t4[4];
        #pragma unroll
        for (int j = 0; j < 4; j++) t4[j] = (f16)v[j];
        *(uint2*)((f16*)C + (size_t)row * N + col0) = *(uint2*)t4;
      } else {
        float4 t4 = {v[0], v[1], v[2], v[3]};
        *(float4*)((float*)C + (size_t)row * N + col0) = t4;
      }
    }
  }
}

template<typename OutT, int RELU, int BM, int BN, int VTSTART, int K>
__global__ __launch_bounds__(BM * 2, 4) void gemm_f16(
    const f16* __restrict__ A, const f16* __restrict__ Bt,
    const float* __restrict__ bias, OutT* __restrict__ C,
    int N, const int* __restrict__ rowmap, f16* __restrict__ vt)
{
  gemm_body<OutT, RELU, BM, BN, VTSTART, K>(A, Bt, bias, C, N, rowmap, vt,
                                            blockIdx.x, blockIdx.y, K, K);
}

// ---------------------------------------------------------------------------
// merged cKV GEMM (512 blocks, V^T out) + gather-fused cQ GEMM (64 blocks)
// ---------------------------------------------------------------------------
__global__ __launch_bounds__(256, 4) void ckv_cq_kernel(
    const f16* __restrict__ X, const f16* __restrict__ CKVT,
    const float* __restrict__ bckv, f16* __restrict__ CKV,
    f16* __restrict__ vt2, const f16* __restrict__ cWqT,
    const float* __restrict__ cbq, f16* __restrict__ CQ,
    const int* __restrict__ pidx)
{
  int bid = blockIdx.x;
  if (bid < 512) {
    gemm_body<f16, 0, 128, 128, 512, 512>(X, CKVT, bckv, CKV, 1024,
                                          nullptr, vt2, bid >> 3, bid & 7, 512, 512);
  } else {
    bid -= 512;
    gemm_body<f16, 0, 128, 64, -1, 512>(X, cWqT, cbq, CQ, 512,
                                        pidx, nullptr, bid >> 3, bid & 7, 512, 512);
  }
}

// ---------------------------------------------------------------------------
// final projection, split-K x4
// ---------------------------------------------------------------------------
__global__ __launch_bounds__(256, 4) void co_splitk(
    const f16* __restrict__ A, const f16* __restrict__ Bt,
    float* __restrict__ part)
{
  const int z = blockIdx.z;
  gemm_body<float, 0, 128, 64, -1, 128>(A + z * 128, Bt + z * 128, nullptr,
      part + (size_t)z * NP_ * 512, 512, nullptr, nullptr,
      blockIdx.x, blockIdx.y, 512, 512);
}

__global__ __launch_bounds__(128) void co_reduce(
    const float* __restrict__ part, const float* __restrict__ bias,
    float* __restrict__ out)
{
  const int row = blockIdx.x;
  const int col = threadIdx.x * 4;
  float4 s = *(const float4*)(bias + col);
  #pragma unroll
  for (int c = 0; c < 4; c++) {
    const float4 v = *(const float4*)(part + ((size_t)c * NP_ + row) * 512 + col);
    s.x += v.x; s.y += v.y; s.z += v.z; s.w += v.w;
  }
  *(float4*)(out + (size_t)row * 512 + col) = s;
}

// ---------------------------------------------------------------------------
// f16 MFMA flash attention (same as round 12)
// ---------------------------------------------------------------------------
template<int QG, int CHUNKS>
__global__ __launch_bounds__(256) void attn_f16(
    const f16* __restrict__ Q, int qs,
    const f16* __restrict__ Kp, int kvs,
    const f16* __restrict__ VT, f16* __restrict__ O,
    float* __restrict__ Opart, float* __restrict__ Lpart, int NQ)
{
  constexpr int CL = S_ / CHUNKS;
  constexpr int NT = CL / 64;
  __shared__ __align__(16) f16 Ks[2][64][76];
  __shared__ __align__(16) f16 VtL[2][64 * 64];

  const int tid = threadIdx.x;
  const int w = tid >> 6, l = tid & 63;
  const int lo4 = l & 15, hi2 = l >> 4;
  const int lin = (CHUNKS == 1) ? blockIdx.x : (blockIdx.x & 127);
  const int c   = (CHUNKS == 1) ? 0 : (int)(blockIdx.x >> 7);
  const int h = lin & 7, b = (lin >> 3) & 3, qt = lin >> 5;

  const f16 qscale = (f16)0.18033688f;   // 0.125 * log2(e)
  f16x8 qf[QG][2];
  #pragma unroll
  for (int qg = 0; qg < QG; qg++) {
    const int qrow = qt * (64 * QG) + w * (16 * QG) + qg * 16 + lo4;
    const f16* Qp = Q + (size_t)(b * NQ + qrow) * qs + h * DH_ + hi2 * 8;
    qf[qg][0] = *(const f16x8*)(Qp);
    qf[qg][1] = *(const f16x8*)(Qp + 32);
    #pragma unroll
    for (int i = 0; i < 8; i++) { qf[qg][0][i] *= qscale; qf[qg][1][i] *= qscale; }
  }

  const int g2 = lo4 >> 2, j4 = lo4 & 3;
  const int kvp0 = 8 * g2 + j4;
  const int kvp1 = 8 * (g2 ^ 2) + 4 + j4;
  const int pidx = (l ^ 32) << 2;
  const int vswz = lo4 & 7;

  const f16* Kb = Kp + ((size_t)b * S_ + c * CL) * kvs + h * DH_;
  const f16* VTbh = VT + (((size_t)(b * 8 + h)) << 17) + c * CL;

  float lsum[QG];
  f32x4 oacc[QG][4];
  #pragma unroll
  for (int qg = 0; qg < QG; qg++) {
    lsum[qg] = 0.f;
    #pragma unroll
    for (int df = 0; df < 4; df++) oacc[qg][df] = (f32x4){0.f, 0.f, 0.f, 0.f};
  }

  const int r0 = tid >> 3;
  const int c8 = tid & 7;

  #pragma unroll
  for (int i = 0; i < 2; i++) {
    int r = i * 32 + r0;
    GLDS16(VTbh + (size_t)r * 2048 + ((c8 ^ (r & 7)) * 8), &VtL[0][(i * 256 + tid) * 8]);
  }
  f16x8 kreg[2];
  #pragma unroll
  for (int i = 0; i < 2; i++)
    kreg[i] = *(const f16x8*)(Kb + (size_t)(i * 32 + r0) * kvs + c8 * 8);
  #pragma unroll
  for (int i = 0; i < 2; i++)
    *(f16x8*)(&Ks[0][i * 32 + r0][c8 * 8]) = kreg[i];
  __syncthreads();

  int cur = 0;
  for (int t = 0; t < NT; t++) {
    if (t + 1 < NT) {
      const int kt2 = (t + 1) * 64;
      #pragma unroll
      for (int i = 0; i < 2; i++) {
        int r = i * 32 + r0;
        GLDS16(VTbh + (size_t)r * 2048 + kt2 + ((c8 ^ (r & 7)) * 8),
               &VtL[cur ^ 1][(i * 256 + tid) * 8]);
      }
      #pragma unroll
      for (int i = 0; i < 2; i++)
        kreg[i] = *(const f16x8*)(Kb + (size_t)(kt2 + i * 32 + r0) * kvs + c8 * 8);
    }
    f32x4 sacc[QG][4];
    #pragma unroll
    for (int nf = 0; nf < 4; nf++) {
      const int krow = ((nf & 1) ? kvp1 : kvp0) + (nf >> 1) * 32;
      f16x8 kf0 = *(const f16x8*)(&Ks[cur][krow][hi2 * 8]);
      f16x8 kf1 = *(const f16x8*)(&Ks[cur][krow][32 + hi2 * 8]);
      #pragma unroll
      for (int qg = 0; qg < QG; qg++) {
        f32x4 s = (f32x4){0.f, 0.f, 0.f, 0.f};
        s = MFMA16(kf0, qf[qg][0], s);
        s = MFMA16(kf1, qf[qg][1], s);
        sacc[qg][nf] = s;
      }
    }
    uint32_t packs[QG][4][2];
    #pragma unroll
    for (int qg = 0; qg < QG; qg++)
      #pragma unroll
      for (int nf = 0; nf < 4; nf++) {
        float p0 = exp2f(sacc[qg][nf][0]);
        float p1 = exp2f(sacc[qg][nf][1]);
        float p2 = exp2f(sacc[qg][nf][2]);
        float p3 = exp2f(sacc[qg][nf][3]);
        lsum[qg] += (p0 + p1) + (p2 + p3);
        packs[qg][nf][0] = __builtin_bit_cast(uint32_t, __builtin_amdgcn_cvt_pkrtz(p0, p1));
        packs[qg][nf][1] = __builtin_bit_cast(uint32_t, __builtin_amdgcn_cvt_pkrtz(p2, p3));
      }
    #pragma unroll
    for (int ks = 0; ks < 2; ks++) {
      f16x8 pb[QG];
      #pragma unroll
      for (int qg = 0; qg < QG; qg++) {
        uint32_t w0 = packs[qg][2 * ks][0];
        uint32_t w1 = packs[qg][2 * ks][1];
        uint32_t w2 = (uint32_t)__builtin_amdgcn_ds_bpermute(pidx, (int)packs[qg][2 * ks + 1][0]);
        uint32_t w3 = (uint32_t)__builtin_amdgcn_ds_bpermute(pidx, (int)packs[qg][2 * ks + 1][1]);
        u32x4 bw = (u32x4){w0, w1, w2, w3};
        pb[qg] = __builtin_bit_cast(f16x8, bw);
      }
      #pragma unroll
      for (int df = 0; df < 4; df++) {
        const int r = df * 16 + lo4;
        const int cc = (ks * 4 + hi2) ^ vswz;
        f16x8 vf = *(const f16x8*)(&VtL[cur][r * 64 + cc * 8]);
        #pragma unroll
        for (int qg = 0; qg < QG; qg++)
          oacc[qg][df] = MFMA16(vf, pb[qg], oacc[qg][df]);
      }
    }
    if (t + 1 < NT) {
      #pragma unroll
      for (int i = 0; i < 2; i++)
        *(f16x8*)(&Ks[cur ^ 1][i * 32 + r0][c8 * 8]) = kreg[i];
    }
    __syncthreads();
    cur ^= 1;
  }

  #pragma unroll
  for (int qg = 0; qg < QG; qg++) {
    float r = lsum[qg];
    r += __shfl_xor(r, 16, 64);
    r += __shfl_xor(r, 32, 64);
    const int orow = qt * (64 * QG) + w * (16 * QG) + qg * 16 + lo4;
    if constexpr (CHUNKS == 1) {
      const float invl = 1.0f / r;
      f16* Ob = O + (size_t)(b * NQ + orow) * D_ + h * DH_ + hi2 * 4;
      #pragma unroll
      for (int df = 0; df < 4; df++) {
        f16 t4[4];
        #pragma unroll
        for (int j = 0; j < 4; j++) t4[j] = (f16)(oacc[qg][df][j] * invl);
        *(uint2*)(Ob + df * 16) = *(uint2*)t4;
      }
    } else {
      float* Op = Opart + ((size_t)c * NP_ + b * NQ + orow) * D_ + h * DH_ + hi2 * 4;
      #pragma unroll
      for (int df = 0; df < 4; df++) {
        float4 v = {oacc[qg][df][0], oacc[qg][df][1], oacc[qg][df][2], oacc[qg][df][3]};
        *(float4*)(Op + df * 16) = v;
      }
      if (hi2 == 0)
        Lpart[((size_t)c * NP_ + b * NQ + orow) * H_ + h] = r;
    }
  }
}

// ---------------------------------------------------------------------------
__global__ __launch_bounds__(128) void attn_reduce(
    const float* __restrict__ Opart, const float* __restrict__ Lpart,
    f16* __restrict__ CO)
{
  const int row = blockIdx.x;
  const int col = threadIdx.x * 4;
  const int h = col >> 6;
  float4 o = {0.f, 0.f, 0.f, 0.f};
  float ls = 0.f;
  #pragma unroll
  for (int c = 0; c < 4; c++) {
    const float4 v = *(const float4*)(Opart + ((size_t)c * NP_ + row) * D_ + col);
    o.x += v.x; o.y += v.y; o.z += v.z; o.w += v.w;
    ls += Lpart[((size_t)c * NP_ + row) * H_ + h];
  }
  const float inv = 1.0f / ls;
  f16 t4[4];
  t4[0] = (f16)(o.x * inv); t4[1] = (f16)(o.y * inv);
  t4[2] = (f16)(o.z * inv); t4[3] = (f16)(o.w * inv);
  *(uint2*)(CO + (size_t)row * D_ + col) = *(uint2*)t4;
}

// ---------------------------------------------------------------------------
__global__ __launch_bounds__(256) void ln_kernel(
    const f16* __restrict__ a, const f16* __restrict__ r,
    const float* __restrict__ g, const float* __restrict__ be,
    f16* __restrict__ out)
{
  const int row = blockIdx.x * 2 + (threadIdx.x >> 7);
  const int t = threadIdx.x & 127;
  const f16* ap = a + (size_t)row * D_ + t * 4;
  const f16* rp = r + (size_t)row * D_ + t * 4;
  uint2 au = *(const uint2*)ap, ru = *(const uint2*)rp;
  f16 a4[4], r4[4];
  *(uint2*)a4 = au; *(uint2*)r4 = ru;
  float x0 = (float)a4[0] + (float)r4[0];
  float x1 = (float)a4[1] + (float)r4[1];
  float x2 = (float)a4[2] + (float)r4[2];
  float x3 = (float)a4[3] + (float)r4[3];
  float sm = x0 + x1 + x2 + x3;
  float sq = x0*x0 + x1*x1 + x2*x2 + x3*x3;
  #pragma unroll
  for (int off = 32; off > 0; off >>= 1) {
    sm += __shfl_down(sm, off, 64);
    sq += __shfl_down(sq, off, 64);
  }
  __shared__ float s0[4], s1[4];
  if ((threadIdx.x & 63) == 0) { s0[threadIdx.x >> 6] = sm; s1[threadIdx.x >> 6] = sq; }
  __syncthreads();
  const int base = (threadIdx.x >> 7) * 2;
  const float Sm = s0[base] + s0[base + 1];
  const float Sq = s1[base] + s1[base + 1];
  const float mean = Sm * (1.0f / 512.0f);
  const float var  = Sq * (1.0f / 512.0f) - mean * mean;
  const float inv  = rsqrtf(var + 1e-5f);
  const float4 vg = *(const float4*)(g + t * 4);
  const float4 vb = *(const float4*)(be + t * 4);
  f16 o4[4];
  o4[0] = (f16)(vg.x * (x0 - mean) * inv + vb.x);
  o4[1] = (f16)(vg.y * (x1 - mean) * inv + vb.y);
  o4[2] = (f16)(vg.z * (x2 - mean) * inv + vb.z);
  o4[3] = (f16)(vg.w * (x3 - mean) * inv + vb.w);
  *(uint2*)(out + (size_t)row * D_ + t * 4) = *(uint2*)o4;
}

// ---------------------------------------------------------------------------
extern "C" void kernel_launch(void* const* d_in, const int* in_sizes, int n_in,
                              void* d_out, int out_size, void* d_ws, size_t ws_size,
                              hipStream_t stream) {
  const int*   bytes_seq = (const int*)  d_in[0];
  const int*   patch_idx = (const int*)  d_in[1];
  const float* byte_emb  = (const float*)d_in[2];
  const float* ngram_emb = (const float*)d_in[3];
  const float* sWq = (const float*)d_in[4];  const float* sbq = (const float*)d_in[5];
  const float* sWk = (const float*)d_in[6];  const float* sbk = (const float*)d_in[7];
  const float* sWv = (const float*)d_in[8];  const float* sbv = (const float*)d_in[9];
  const float* sWo = (const float*)d_in[10]; const float* sbo = (const float*)d_in[11];
  const float* ln1g = (const float*)d_in[12]; const float* ln1b = (const float*)d_in[13];
  const float* W1 = (const float*)d_in[14];  const float* b1 = (const float*)d_in[15];
  const float* W2 = (const float*)d_in[16];  const float* b2 = (const float*)d_in[17];
  const float* ln2g = (const float*)d_in[18]; const float* ln2b = (const float*)d_in[19];
  const float* cWq = (const float*)d_in[20]; const float* cbq = (const float*)d_in[21];
  const float* cWk = (const float*)d_in[22]; const float* cbk = (const float*)d_in[23];
  const float* cWv = (const float*)d_in[24]; const float* cbv = (const float*)d_in[25];
  const float* cWo = (const float*)d_in[26]; const float* cbo = (const float*)d_in[27];

  char* base = (char*)d_ws;
  const size_t MB = 1u << 20;
  f16* E16     = (f16*)(base + 0 * MB);
  f16* TMP16   = (f16*)(base + 8 * MB);
  f16* X116    = (f16*)(base + 16 * MB);
  f16* X216    = (f16*)(base + 24 * MB);
  f16* QKV16   = (f16*)(base + 32 * MB);
  f16* AT16    = (f16*)(base + 56 * MB);
  f16* HID16   = (f16*)(base + 64 * MB);
  f16* CKV16   = (f16*)(base + 96 * MB);
  f16* CQ16    = (f16*)(base + 112 * MB);
  f16* CO16    = (f16*)(base + 113 * MB);
  f16* WT      = (f16*)(base + 114 * MB);
  float* bqkv  = (float*)(base + 123 * MB);
  float* bckv  = bqkv + 1536;
  f16* VT      = (f16*)(base + 124 * MB);
  f16* VT2     = (f16*)(base + 132 * MB);
  float* OPART = (float*)(base + 140 * MB);
  float* LPART = (float*)(base + 148 * MB);

  f16* QKVT = WT;
  f16* sWoT = QKVT + 786432;
  f16* W1T  = sWoT + 262144;
  f16* W2T  = W1T + 1048576;
  f16* cWqT = W2T + 1048576;
  f16* CKVT = cWqT + 262144;
  f16* cWoT = CKVT + 524288;

  WJobs wj;
  {
    const float* wsrc[10] = {sWq, sWk, sWv, sWo, W1, W2, cWq, cWk, cWv, cWo};
    f16* wdst[10] = {QKVT, QKVT + 262144, QKVT + 524288, sWoT, W1T, W2T,
                     cWqT, CKVT, CKVT + 262144, cWoT};
    const int wK[10] = {512,512,512,512, 512,2048, 512,512,512,512};
    const int wN[10] = {512,512,512,512, 2048,512, 512,512,512,512};
    for (int i = 0; i < 10; i++) {
      wj.src[i] = wsrc[i]; wj.dst[i] = wdst[i];
      wj.K[i] = wK[i]; wj.N[i] = wN[i];
      wj.tiles[i] = (wK[i] >> 5) * (wN[i] >> 5);
    }
  }

  const dim3 blk512(512), blk256(256), blk128(128);

  prep_kernel<<<10240 + 10 + 4096, blk256, 0, stream>>>(
      wj, sbq, sbk, sbv, cbk, cbv, bqkv, bckv,
      bytes_seq, byte_emb, ngram_emb, E16);

  // fused QKV projection (BM=256, 8-wave: halves A staging traffic)
  gemm_f16<f16, 0, 256, 128, 1024, 512><<<dim3(32, 12), blk512, 0, stream>>>(
      E16, QKVT, bqkv, QKV16, 1536, nullptr, VT);

  // self-attention (128 q/block)
  attn_f16<2, 1><<<512, blk256, 0, stream>>>(
      QKV16, 1536, QKV16 + 512, 1536, VT, AT16, nullptr, nullptr, S_);

  // output projection + LN1
  gemm_f16<f16, 0, 128, 64, -1, 512><<<dim3(64, 8), blk256, 0, stream>>>(
      AT16, sWoT, sbo, TMP16, 512, nullptr, nullptr);
  ln_kernel<<<N_/2, blk256, 0, stream>>>(E16, TMP16, ln1g, ln1b, X116);

  // FFN (FFN1 BM=256)
  gemm_f16<f16, 1, 256, 128, -1, 512><<<dim3(32, 16), blk512, 0, stream>>>(
      X116, W1T, b1, HID16, 2048, nullptr, nullptr);
  gemm_f16<f16, 0, 128, 64, -1, 2048><<<dim3(64, 8), blk256, 0, stream>>>(
      HID16, W2T, b2, TMP16, 512, nullptr, nullptr);
  ln_kernel<<<N_/2, blk256, 0, stream>>>(X116, TMP16, ln2g, ln2b, X216);

  // cross: fused K|V projection (V^T to VT2) + gather-fused Q proj
  ckv_cq_kernel<<<576, blk256, 0, stream>>>(
      X216, CKVT, bckv, CKV16, VT2, cWqT, cbq, CQ16, patch_idx);
  attn_f16<1, 4><<<512, blk256, 0, stream>>>(
      CQ16, 512, CKV16, 1024, VT2, nullptr, OPART, LPART, P_);
  attn_reduce<<<NP_, blk128, 0, stream>>>(OPART, LPART, CO16);

  // final projection: split-K x4, reduce+bias -> d_out
  co_splitk<<<dim3(8, 8, 4), blk256, 0, stream>>>(CO16, cWoT, OPART);
  co_reduce<<<NP_, blk128, 0, stream>>>(OPART, cbo, (float*)d_out);
}